// Round 2
// baseline (96.486 us; speedup 1.0000x reference)
//
#include <hip/hip_runtime.h>

// GaussianEM R6: two-dispatch, zero-atomic, zero-memset; latency-overlap polish.
//
// loss = sum_{c,d}(means[LAST][d]-mean_param[c][d])^2 + cov_sq_last(~1e-10, skipped)
//        + sum(cov_param^2)
//
// Structure (R5, validated at 95.6us): K1 (128 blocks) plain-stores per-block
// partials {64 feature sums, count, covsum} to private ws slots (no init needed,
// no atomics, no fences); block 0 also computes the data-independent mean_param
// terms (colsum[d], sum(mp^2)) overlapped with the other blocks. K2 (1 block)
// reduces the 128 slots and finishes via the algebraic hoist:
//   sum_{c,d}(m-P)^2 = C*sum m^2 - 2*sum_d m_d*colsum_d + sum P^2.
// Inter-kernel visibility is stream-order guaranteed (G16-safe).
//
// R6 deltas (pure critical-path latency):
//  - K1: cov_param float4s and block-0 mean_param loads are issued into registers
//    BEFORE the target->ballot->gather dependent chain (the while(m) loop's
//    unknown trip count otherwise blocks the compiler from hoisting them), so all
//    independent cold-HBM rounds overlap the 2-round gather chain.
//  - K2: colsum / sum(mp^2) loads hoisted to kernel entry (were a dependent tail
//    round after __syncthreads).
//  - K1: scalar slot stores fused to one float2.
//
// ws layout (floats): slot b at [b*68]: [0..63]=sums, [64]=count, [65]=covsum.
//                     [128*68 + 0..63]=colsum, [128*68+64]=sum(mean_param^2).

#define DIM 64
#define NCLASSES 128
#define LAST (NCLASSES - 1)
#define NBLOCKS 128
#define BLOCK 512                      // 8 waves/block; 1024 waves total
#define NWAVES (NBLOCKS * 8)
#define SLOT 68                        // 66 used + pad to 16B multiple
#define COLBASE (NBLOCKS * SLOT)
#define MP_PER_THREAD ((NCLASSES * DIM) / BLOCK)   // 16

__global__ __launch_bounds__(BLOCK) void gem_part(
    const float* __restrict__ inputs, const int* __restrict__ target,
    const float* __restrict__ mean_param, const float* __restrict__ cov_param,
    int n, int cov_n4, float* __restrict__ ws)
{
    const int tid  = threadIdx.x;
    const int lane = tid & 63;
    const int wib  = tid >> 6;                 // wave in block (0..7)
    const int b    = blockIdx.x;
    const int gwave = b * 8 + wib;             // 0..1023

    // ---- issue ALL independent loads first (overlap their cold-miss latency
    //      with the dependent target->gather chain below) ----
    const float4* c4 = (const float4*)cov_param;
    const int ci = b * BLOCK + tid;
    float4 v0 = {0.f, 0.f, 0.f, 0.f}, v1 = {0.f, 0.f, 0.f, 0.f};
    if (ci < cov_n4)                  v0 = c4[ci];
    if (ci + NBLOCKS * BLOCK < cov_n4) v1 = c4[ci + NBLOCKS * BLOCK];

    float mp[MP_PER_THREAD];
    if (b == 0) {
        #pragma unroll
        for (int k = 0; k < MP_PER_THREAD; ++k)
            mp[k] = mean_param[tid + k * BLOCK];          // d = tid&63 fixed
    }

    // ---- target scan: one int4 load per lane covers 256 samples per wave ----
    float acc = 0.f;
    int   cnt = 0;
    for (int base = gwave * 256; base < n; base += NWAVES * 256) {   // 1 iter at n=262144
        const int4 t4 = *(const int4*)(target + base + lane * 4);    // 16B coalesced
        unsigned long long m0 = __ballot(t4.x == LAST);
        unsigned long long m1 = __ballot(t4.y == LAST);
        unsigned long long m2 = __ballot(t4.z == LAST);
        unsigned long long m3 = __ballot(t4.w == LAST);
        cnt += __popcll(m0) + __popcll(m1) + __popcll(m2) + __popcll(m3);
        #pragma unroll
        for (int j = 0; j < 4; ++j) {
            unsigned long long m = (j == 0) ? m0 : (j == 1) ? m1 : (j == 2) ? m2 : m3;
            while (m) {
                int bit = __ffsll(m) - 1;
                m &= m - 1;
                acc += inputs[(size_t)(base + 4 * bit + j) * DIM + lane]; // lane = dim
            }
        }
    }

    // ---- fold the pre-issued loads ----
    float csum = v0.x * v0.x + v0.y * v0.y + v0.z * v0.z + v0.w * v0.w
               + v1.x * v1.x + v1.y * v1.y + v1.z * v1.z + v1.w * v1.w;
    for (int off = 32; off; off >>= 1) csum += __shfl_down(csum, off, 64);

    float pcol = 0.f, psq = 0.f;
    if (b == 0) {
        #pragma unroll
        for (int k = 0; k < MP_PER_THREAD; ++k) {
            pcol += mp[k];
            psq  += mp[k] * mp[k];
        }
    }
    for (int off = 32; off; off >>= 1) psq += __shfl_down(psq, off, 64);

    __shared__ float sacc[8][DIM];
    __shared__ float scol[8][DIM];
    __shared__ float scov[8], spsq[8];
    __shared__ int   scnt[8];
    sacc[wib][lane] = acc;
    scol[wib][lane] = pcol;
    if (lane == 0) { scov[wib] = csum; scnt[wib] = cnt; spsq[wib] = psq; }
    __syncthreads();

    // ---- publish: plain coalesced stores to a private slot (no atomics) ----
    if (wib == 0) {
        float s = 0.f;
        #pragma unroll
        for (int w = 0; w < 8; ++w) s += sacc[w][lane];
        ws[b * SLOT + lane] = s;                       // 256B coalesced store
        if (b == 0) {
            float cs = 0.f;
            #pragma unroll
            for (int w = 0; w < 8; ++w) cs += scol[w][lane];
            ws[COLBASE + lane] = cs;
        }
    }
    if (tid == 0) {
        int   c  = 0;   float cv = 0.f, q = 0.f;
        #pragma unroll
        for (int w = 0; w < 8; ++w) { c += scnt[w]; cv += scov[w]; q += spsq[w]; }
        *(float2*)(ws + b * SLOT + DIM) = make_float2((float)c, cv);
        if (b == 0) ws[COLBASE + DIM] = q;
    }
}

__global__ __launch_bounds__(BLOCK) void gem_final(
    const float* __restrict__ ws, float* __restrict__ out)
{
    const int tid  = threadIdx.x;
    const int lane = tid & 63;
    const int g    = tid >> 6;                 // 0..7

    // ---- hoisted independent loads (overlap with the slot-reduce round) ----
    const float col = (tid < DIM)  ? ws[COLBASE + tid] : 0.f;
    const float psq = (tid == 0)   ? ws[COLBASE + DIM] : 0.f;

    // reduce 128 slots: thread (g,lane) sums blocks {g, g+8, ..., g+120} at dim=lane
    float s = 0.f;
    #pragma unroll
    for (int j = 0; j < NBLOCKS / 8; ++j)
        s += ws[(g + 8 * j) * SLOT + lane];    // 256B coalesced per wave

    // counts / covsums: threads 0..127 each pick up one slot's scalar pair
    float c = 0.f, cv = 0.f;
    if (tid < NBLOCKS) {
        float2 p = *(const float2*)(ws + tid * SLOT + DIM);
        c = p.x; cv = p.y;
    }
    for (int off = 32; off; off >>= 1) {
        c  += __shfl_down(c,  off, 64);
        cv += __shfl_down(cv, off, 64);
    }

    __shared__ float red[8][DIM];
    __shared__ float scc[2][2];
    __shared__ float spq;
    red[g][lane] = s;
    if (tid < NBLOCKS && lane == 0) { scc[g][0] = c; scc[g][1] = cv; }
    if (tid == 0) spq = psq;
    __syncthreads();

    if (tid < DIM) {                           // wave 0 finishes alone
        float tot = 0.f;
        #pragma unroll
        for (int w = 0; w < 8; ++w) tot += red[w][tid];
        const float count = scc[0][0] + scc[1][0];
        const float covs  = scc[0][1] + scc[1][1];
        const float mean  = tot / count;
        // sum_{c,d}(mean_d - P_{c,d})^2 = C*sum mean^2 - 2*sum mean*colsum + sum P^2
        float d = (float)NCLASSES * mean * mean - 2.f * mean * col;
        for (int off = 32; off; off >>= 1) d += __shfl_down(d, off, 64);
        if (tid == 0) out[0] = d + covs + spq;
    }
}

extern "C" void kernel_launch(void* const* d_in, const int* in_sizes, int n_in,
                              void* d_out, int out_size, void* d_ws, size_t ws_size,
                              hipStream_t stream) {
    const float* inputs     = (const float*)d_in[0];
    const int*   target     = (const int*)d_in[1];
    const float* mean_param = (const float*)d_in[2];
    const float* cov_param  = (const float*)d_in[3];
    float* out = (float*)d_out;
    float* ws  = (float*)d_ws;

    const int n     = in_sizes[0] / DIM;   // 262144
    const int cov_n = in_sizes[3];         // 128*64*64 = 524288

    // no memset: every ws location K2 reads is plain-stored by K1 this launch
    gem_part<<<NBLOCKS, BLOCK, 0, stream>>>(inputs, target, mean_param, cov_param,
                                            n, cov_n / 4, ws);
    gem_final<<<1, BLOCK, 0, stream>>>(ws, out);
}

// Round 4
// 94.606 us; speedup vs baseline: 1.0199x; 1.0199x over previous
//
#include <hip/hip_runtime.h>

// GaussianEM R7b: identical to R7 (R3 bench was an infra failure: container
// failed twice, no pytest/profile output; kernel audit found no fault/hang:
// barriers are block-uniform, all indexing bounds-checked, ws contract matches
// the R5/R6 versions that passed). Re-running the R7 experiment.
//
// loss = sum_{c,d}(means[LAST][d]-mean_param[c][d])^2 + cov_sq_last(~1e-10, skipped)
//        + sum(cov_param^2)
//
// R5/R6 established: timed graph = 2 harness poison fills (~85us, HBM-roofline,
// untouchable) + ~11us controllable slice. R6's independent-load hoist was
// neutral -> the critical path is the GATHER: while(m){acc+=load} emits one
// serialized cold-HBM round (~0.43us) per matching sample; max matches per wave
// over 1024 waves ~ 10 => ~4.5us serial.
//
// R7 restructure:
//  - ballot masks -> per-lane prefix ranks (popc, pure VALU) -> index list in LDS
//    => known trip count, no latency in extraction.
//  - ONE list per BLOCK (2048 samples, max count over 128 blocks ~35), split
//    across 8 waves strided => worst wave ~5 gathers; hand-unrolled x4 with
//    clamped indices => all 4 loads in flight per round => 1-2 serial HBM rounds.
//  - everything else (slot publish, K2 reduce, algebraic mean_param hoist)
//    unchanged from the validated R5/R6 structure.
//
// ws layout (floats): slot b at [b*68]: [0..63]=sums, [64]=count, [65]=covsum.
//                     [128*68 + 0..63]=colsum, [128*68+64]=sum(mean_param^2).

#define DIM 64
#define NCLASSES 128
#define LAST (NCLASSES - 1)
#define NBLOCKS 128
#define BLOCK 512                      // 8 waves/block; 1024 waves total
#define NWAVES (NBLOCKS * 8)
#define CHUNK (BLOCK * 4)              // samples per block per pass = 2048
#define SLOT 68                        // 66 used + pad to 16B multiple
#define COLBASE (NBLOCKS * SLOT)
#define MP_PER_THREAD ((NCLASSES * DIM) / BLOCK)   // 16

__global__ __launch_bounds__(BLOCK) void gem_part(
    const float* __restrict__ inputs, const int* __restrict__ target,
    const float* __restrict__ mean_param, const float* __restrict__ cov_param,
    int n, int cov_n4, float* __restrict__ ws)
{
    const int tid  = threadIdx.x;
    const int lane = tid & 63;
    const int wib  = tid >> 6;                 // wave in block (0..7)
    const int b    = blockIdx.x;

    // ---- independent loads issued first (overlap with target chain) ----
    const float4* c4 = (const float4*)cov_param;
    const int ci = b * BLOCK + tid;
    float4 v0 = {0.f, 0.f, 0.f, 0.f}, v1 = {0.f, 0.f, 0.f, 0.f};
    if (ci < cov_n4)                   v0 = c4[ci];
    if (ci + NBLOCKS * BLOCK < cov_n4) v1 = c4[ci + NBLOCKS * BLOCK];

    float mp[MP_PER_THREAD];
    if (b == 0) {
        #pragma unroll
        for (int k = 0; k < MP_PER_THREAD; ++k)
            mp[k] = mean_param[tid + k * BLOCK];          // d = tid&63 fixed
    }

    // ---- target scan + block-level index extraction + balanced gather ----
    __shared__ int sidx[CHUNK];                 // worst case: all samples match
    __shared__ int swcnt[8];
    float acc = 0.f;                            // per-(wave,lane=dim) partial
    int   cnt_acc = 0;                          // block count (uniform)

    for (int cbase = b * CHUNK; cbase < n; cbase += NBLOCKS * CHUNK) {  // 1 iter
        const int sbase = cbase + wib * 256 + lane * 4;
        const int4 t4 = *(const int4*)(target + sbase);      // 16B coalesced
        const unsigned long long m0 = __ballot(t4.x == LAST);
        const unsigned long long m1 = __ballot(t4.y == LAST);
        const unsigned long long m2 = __ballot(t4.z == LAST);
        const unsigned long long m3 = __ballot(t4.w == LAST);
        const int c0 = __popcll(m0), c1 = __popcll(m1),
                  c2 = __popcll(m2), c3 = __popcll(m3);
        if (lane == 0) swcnt[wib] = c0 + c1 + c2 + c3;       // uniform per wave
        __syncthreads();

        int woff = 0, tot = 0;
        #pragma unroll
        for (int w = 0; w < 8; ++w) {
            int c = swcnt[w];
            if (w < wib) woff += c;
            tot += c;
        }

        // per-lane ranks within the wave's list segment (pure VALU)
        const unsigned long long lt = (1ULL << lane) - 1ULL;
        const int r0 = __popcll(m0 & lt);
        const int r1 = c0 + __popcll(m1 & lt);
        const int r2 = c0 + c1 + __popcll(m2 & lt);
        const int r3 = c0 + c1 + c2 + __popcll(m3 & lt);
        if (t4.x == LAST) sidx[woff + r0] = sbase + 0;
        if (t4.y == LAST) sidx[woff + r1] = sbase + 1;
        if (t4.z == LAST) sidx[woff + r2] = sbase + 2;
        if (t4.w == LAST) sidx[woff + r3] = sbase + 3;
        __syncthreads();

        // balanced gather: wave w takes list entries {w, w+8, ...}, unrolled x4
        // so 4 row loads are in flight per round (clamped dup indices, masked add)
        for (int i = wib; i < tot; i += 32) {
            const int j1 = i + 8, j2 = i + 16, j3 = i + 24;
            const int s0 = sidx[i];
            const int s1 = sidx[j1 < tot ? j1 : tot - 1];
            const int s2 = sidx[j2 < tot ? j2 : tot - 1];
            const int s3 = sidx[j3 < tot ? j3 : tot - 1];
            const float x0 = inputs[(size_t)s0 * DIM + lane];   // 256B/wave coalesced
            const float x1 = inputs[(size_t)s1 * DIM + lane];
            const float x2 = inputs[(size_t)s2 * DIM + lane];
            const float x3 = inputs[(size_t)s3 * DIM + lane];
            acc += x0;
            if (j1 < tot) acc += x1;
            if (j2 < tot) acc += x2;
            if (j3 < tot) acc += x3;
        }
        cnt_acc += tot;
        __syncthreads();                        // protect sidx/swcnt (multi-iter)
    }

    // ---- fold the pre-issued loads ----
    float csum = v0.x * v0.x + v0.y * v0.y + v0.z * v0.z + v0.w * v0.w
               + v1.x * v1.x + v1.y * v1.y + v1.z * v1.z + v1.w * v1.w;
    for (int off = 32; off; off >>= 1) csum += __shfl_down(csum, off, 64);

    float pcol = 0.f, psq = 0.f;
    if (b == 0) {
        #pragma unroll
        for (int k = 0; k < MP_PER_THREAD; ++k) {
            pcol += mp[k];
            psq  += mp[k] * mp[k];
        }
    }
    for (int off = 32; off; off >>= 1) psq += __shfl_down(psq, off, 64);

    __shared__ float sacc[8][DIM];
    __shared__ float scol[8][DIM];
    __shared__ float scov[8], spsq[8];
    sacc[wib][lane] = acc;
    scol[wib][lane] = pcol;
    if (lane == 0) { scov[wib] = csum; spsq[wib] = psq; }
    __syncthreads();

    // ---- publish: plain coalesced stores to a private slot (no atomics) ----
    if (wib == 0) {
        float s = 0.f;
        #pragma unroll
        for (int w = 0; w < 8; ++w) s += sacc[w][lane];
        ws[b * SLOT + lane] = s;                       // 256B coalesced store
        if (b == 0) {
            float cs = 0.f;
            #pragma unroll
            for (int w = 0; w < 8; ++w) cs += scol[w][lane];
            ws[COLBASE + lane] = cs;
        }
    }
    if (tid == 0) {
        float cv = 0.f, q = 0.f;
        #pragma unroll
        for (int w = 0; w < 8; ++w) { cv += scov[w]; q += spsq[w]; }
        *(float2*)(ws + b * SLOT + DIM) = make_float2((float)cnt_acc, cv);
        if (b == 0) ws[COLBASE + DIM] = q;
    }
}

__global__ __launch_bounds__(BLOCK) void gem_final(
    const float* __restrict__ ws, float* __restrict__ out)
{
    const int tid  = threadIdx.x;
    const int lane = tid & 63;
    const int g    = tid >> 6;                 // 0..7

    // hoisted independent loads (overlap with the slot-reduce round)
    const float col = (tid < DIM) ? ws[COLBASE + tid] : 0.f;
    const float psq = (tid == 0)  ? ws[COLBASE + DIM] : 0.f;

    // reduce 128 slots: thread (g,lane) sums blocks {g, g+8, ..., g+120} at dim=lane
    float s = 0.f;
    #pragma unroll
    for (int j = 0; j < NBLOCKS / 8; ++j)
        s += ws[(g + 8 * j) * SLOT + lane];    // 256B coalesced per wave

    // counts / covsums: threads 0..127 each pick up one slot's scalar pair
    float c = 0.f, cv = 0.f;
    if (tid < NBLOCKS) {
        float2 p = *(const float2*)(ws + tid * SLOT + DIM);
        c = p.x; cv = p.y;
    }
    for (int off = 32; off; off >>= 1) {
        c  += __shfl_down(c,  off, 64);
        cv += __shfl_down(cv, off, 64);
    }

    __shared__ float red[8][DIM];
    __shared__ float scc[2][2];
    __shared__ float spq;
    red[g][lane] = s;
    if (tid < NBLOCKS && lane == 0) { scc[g][0] = c; scc[g][1] = cv; }
    if (tid == 0) spq = psq;
    __syncthreads();

    if (tid < DIM) {                           // wave 0 finishes alone
        float tot = 0.f;
        #pragma unroll
        for (int w = 0; w < 8; ++w) tot += red[w][tid];
        const float count = scc[0][0] + scc[1][0];
        const float covs  = scc[0][1] + scc[1][1];
        const float mean  = tot / count;
        // sum_{c,d}(mean_d - P_{c,d})^2 = C*sum mean^2 - 2*sum mean*colsum + sum P^2
        float d = (float)NCLASSES * mean * mean - 2.f * mean * col;
        for (int off = 32; off; off >>= 1) d += __shfl_down(d, off, 64);
        if (tid == 0) out[0] = d + covs + spq;
    }
}

extern "C" void kernel_launch(void* const* d_in, const int* in_sizes, int n_in,
                              void* d_out, int out_size, void* d_ws, size_t ws_size,
                              hipStream_t stream) {
    const float* inputs     = (const float*)d_in[0];
    const int*   target     = (const int*)d_in[1];
    const float* mean_param = (const float*)d_in[2];
    const float* cov_param  = (const float*)d_in[3];
    float* out = (float*)d_out;
    float* ws  = (float*)d_ws;

    const int n     = in_sizes[0] / DIM;   // 262144
    const int cov_n = in_sizes[3];         // 128*64*64 = 524288

    // no memset: every ws location K2 reads is plain-stored by K1 this launch
    gem_part<<<NBLOCKS, BLOCK, 0, stream>>>(inputs, target, mean_param, cov_param,
                                            n, cov_n / 4, ws);
    gem_final<<<1, BLOCK, 0, stream>>>(ws, out);
}